// Round 1
// baseline (104.863 us; speedup 1.0000x reference)
//
#include <hip/hip_runtime.h>
#include <math.h>

#define D 256
#define TWOD 512
#define BB 1024
#define NN 131072

// ---------------- P0a: MqT = (Wk^T Wq)^T, bqt = Wk^T bq, vq = Wq^T bk, c0 = bk.bq
__global__ __launch_bounds__(256) void p0a_kernel(
    const float* __restrict__ Wq, const float* __restrict__ bq,
    const float* __restrict__ Wk, const float* __restrict__ bk,
    float* __restrict__ MqT, float* __restrict__ bqt,
    float* __restrict__ vq, float* __restrict__ c0) {
  const int t = threadIdx.x;
  const int blk = blockIdx.x;
  if (blk < 64) {
    const int k0 = blk * 4;
    float a0 = 0.f, a1 = 0.f, a2 = 0.f, a3 = 0.f;
    for (int d = 0; d < D; ++d) {
      const float wk = Wk[d * D + t];              // coalesced
      a0 = fmaf(wk, Wq[d * D + k0 + 0], a0);       // uniform -> sgpr
      a1 = fmaf(wk, Wq[d * D + k0 + 1], a1);
      a2 = fmaf(wk, Wq[d * D + k0 + 2], a2);
      a3 = fmaf(wk, Wq[d * D + k0 + 3], a3);
    }
    // MqT[k][h] = sum_d Wq[d,k]*Wk[d,h]
    MqT[(k0 + 0) * D + t] = a0;
    MqT[(k0 + 1) * D + t] = a1;
    MqT[(k0 + 2) * D + t] = a2;
    MqT[(k0 + 3) * D + t] = a3;
  } else {
    float a = 0.f, b = 0.f;
    for (int d = 0; d < D; ++d) {
      a = fmaf(Wk[d * D + t], bq[d], a);
      b = fmaf(Wq[d * D + t], bk[d], b);
    }
    bqt[t] = a;
    vq[t] = b;
    if (t == 0) {
      float cc = 0.f;
      for (int d = 0; d < D; ++d) cc = fmaf(bk[d], bq[d], cc);
      c0[0] = cc;
    }
  }
}

// ---------------- P0b: WfT[k][d]: k<256 -> Wo[d,k]; k>=256 -> (WoB@Wv)[d,k-256]; b2 = WoB@bv + bo
__global__ __launch_bounds__(256) void p0b_kernel(
    const float* __restrict__ Wo, const float* __restrict__ Wv,
    const float* __restrict__ bv, const float* __restrict__ bo,
    float* __restrict__ WfT, float* __restrict__ b2) {
  const int t = threadIdx.x;
  const int blk = blockIdx.x;
  if (blk < 64) {
    // transpose of Wo[:, :256]
    for (int i = 0; i < 4; ++i) {
      const int k = blk * 4 + i;
      WfT[k * D + t] = Wo[t * TWOD + k];
    }
  } else if (blk < 128) {
    const int h0 = (blk - 64) * 4;
    float a0 = 0.f, a1 = 0.f, a2 = 0.f, a3 = 0.f;
    for (int v = 0; v < D; ++v) {
      const float wo = Wo[t * TWOD + D + v];       // per-lane, L1-window pattern
      a0 = fmaf(wo, Wv[v * D + h0 + 0], a0);       // uniform -> sgpr
      a1 = fmaf(wo, Wv[v * D + h0 + 1], a1);
      a2 = fmaf(wo, Wv[v * D + h0 + 2], a2);
      a3 = fmaf(wo, Wv[v * D + h0 + 3], a3);
    }
    WfT[(D + h0 + 0) * D + t] = a0;
    WfT[(D + h0 + 1) * D + t] = a1;
    WfT[(D + h0 + 2) * D + t] = a2;
    WfT[(D + h0 + 3) * D + t] = a3;
  } else {
    float a = bo[t];
    for (int v = 0; v < D; ++v) a = fmaf(Wo[t * TWOD + D + v], bv[v], a);
    b2[t] = a;
  }
}

// ---------------- offsets: lower_bound of each batch id in sorted batch_idx
__global__ __launch_bounds__(256) void koff_kernel(
    const int* __restrict__ bidx, int* __restrict__ offs) {
  const int i = blockIdx.x * blockDim.x + threadIdx.x;
  if (i > BB) return;
  int lo = 0, hi = NN;
  while (lo < hi) {
    const int mid = (lo + hi) >> 1;
    if (bidx[mid] < i) lo = mid + 1; else hi = mid;
  }
  offs[i] = lo;
}

// ---------------- KQ: qt[b] = MqT^T V[b] + bqt ; cQ[b] = vq.V[b] + c0
__global__ __launch_bounds__(256) void kq_kernel(
    const float* __restrict__ V, const float* __restrict__ MqT,
    const float* __restrict__ bqt, const float* __restrict__ vq,
    const float* __restrict__ c0,
    float* __restrict__ qt, float* __restrict__ cQ) {
  __shared__ __align__(16) float Vs[4][D];
  const int t = threadIdx.x;
  const int b0 = blockIdx.x * 4;
  for (int i = 0; i < 4; ++i) Vs[i][t] = V[(b0 + i) * D + t];
  __syncthreads();
  const float binit = bqt[t];
  float a0 = binit, a1 = binit, a2 = binit, a3 = binit;
  for (int k = 0; k < D; k += 4) {
    const float w0 = MqT[(k + 0) * D + t];
    const float w1 = MqT[(k + 1) * D + t];
    const float w2 = MqT[(k + 2) * D + t];
    const float w3 = MqT[(k + 3) * D + t];
    const float4 v0 = *(const float4*)&Vs[0][k];
    const float4 v1 = *(const float4*)&Vs[1][k];
    const float4 v2 = *(const float4*)&Vs[2][k];
    const float4 v3 = *(const float4*)&Vs[3][k];
    a0 = fmaf(w0, v0.x, a0); a0 = fmaf(w1, v0.y, a0); a0 = fmaf(w2, v0.z, a0); a0 = fmaf(w3, v0.w, a0);
    a1 = fmaf(w0, v1.x, a1); a1 = fmaf(w1, v1.y, a1); a1 = fmaf(w2, v1.z, a1); a1 = fmaf(w3, v1.w, a1);
    a2 = fmaf(w0, v2.x, a2); a2 = fmaf(w1, v2.y, a2); a2 = fmaf(w2, v2.z, a2); a2 = fmaf(w3, v2.w, a2);
    a3 = fmaf(w0, v3.x, a3); a3 = fmaf(w1, v3.y, a3); a3 = fmaf(w2, v3.z, a3); a3 = fmaf(w3, v3.w, a3);
  }
  qt[(b0 + 0) * D + t] = a0;
  qt[(b0 + 1) * D + t] = a1;
  qt[(b0 + 2) * D + t] = a2;
  qt[(b0 + 3) * D + t] = a3;
  if (t < 4) {
    float cc = c0[0];
    for (int k = 0; k < D; ++k) cc = fmaf(vq[k], Vs[t][k], cc);
    cQ[b0 + t] = cc;
  }
}

// ---------------- K1: flash-style per-batch pass over contiguous H rows
__global__ __launch_bounds__(256) void k1_kernel(
    const float* __restrict__ H, const float* __restrict__ qt,
    const float* __restrict__ cQ, const int* __restrict__ offs,
    float* __restrict__ sArr) {
  const int b = blockIdx.x;
  const int t = threadIdx.x;
  const int wave = t >> 6;
  const int lane = t & 63;
  const int start = offs[b];
  const int end = offs[b + 1];
  if (start >= end) { sArr[b * D + t] = 0.f; return; }

  const float4 q4 = *(const float4*)&qt[b * D + lane * 4];
  const float cb = cQ[b];
  const float scale = 0.0625f;  // 1/sqrt(256)

  float m = -INFINITY, den = 0.f;
  float ax = 0.f, ay = 0.f, az = 0.f, aw = 0.f;

  int n = start + wave;
  float4 cur = make_float4(0.f, 0.f, 0.f, 0.f);
  if (n < end) cur = *(const float4*)&H[n * D + lane * 4];
  while (n < end) {
    const int nn = n + 4;
    float4 nxt = cur;
    if (nn < end) nxt = *(const float4*)&H[nn * D + lane * 4];  // prefetch

    float p = cur.x * q4.x;
    p = fmaf(cur.y, q4.y, p);
    p = fmaf(cur.z, q4.z, p);
    p = fmaf(cur.w, q4.w, p);
    p += __shfl_xor(p, 32);
    p += __shfl_xor(p, 16);
    p += __shfl_xor(p, 8);
    p += __shfl_xor(p, 4);
    p += __shfl_xor(p, 2);
    p += __shfl_xor(p, 1);
    const float score = (p + cb) * scale;

    const float nm = fmaxf(m, score);
    const float f = __expf(m - nm);      // first iter: exp(-inf) = 0
    const float w = __expf(score - nm);
    den = den * f + w;
    ax = fmaf(w, cur.x, ax * f);
    ay = fmaf(w, cur.y, ay * f);
    az = fmaf(w, cur.z, az * f);
    aw = fmaf(w, cur.w, aw * f);
    m = nm;

    cur = nxt;
    n = nn;
  }

  __shared__ float sm[4], sd[4];
  __shared__ __align__(16) float ss[4][D];
  ss[wave][lane * 4 + 0] = ax;
  ss[wave][lane * 4 + 1] = ay;
  ss[wave][lane * 4 + 2] = az;
  ss[wave][lane * 4 + 3] = aw;
  if (lane == 0) { sm[wave] = m; sd[wave] = den; }
  __syncthreads();

  const float M = fmaxf(fmaxf(sm[0], sm[1]), fmaxf(sm[2], sm[3]));
  float Dn = 0.f, val = 0.f;
  for (int w2 = 0; w2 < 4; ++w2) {
    const float f = __expf(sm[w2] - M);   // empty wave: exp(-inf)=0
    Dn = fmaf(sd[w2], f, Dn);
    val = fmaf(ss[w2][t], f, val);
  }
  sArr[b * D + t] = val / Dn;
}

// ---------------- K2: out[b] = WfT^T [V[b]; s[b]] + b2 ; passthrough for empty graphs
__global__ __launch_bounds__(512) void k2_kernel(
    const float* __restrict__ V, const float* __restrict__ sArr,
    const float* __restrict__ WfT, const float* __restrict__ b2,
    const int* __restrict__ offs, float* __restrict__ out) {
  __shared__ __align__(16) float Us[4][TWOD];
  __shared__ float part[4][D];
  const int t = threadIdx.x;
  const int b0 = blockIdx.x * 4;
  for (int i = 0; i < 4; ++i) {
    float v;
    if (t < D) v = V[(b0 + i) * D + t];
    else v = sArr[(b0 + i) * D + (t - D)];
    Us[i][t] = v;
  }
  __syncthreads();
  const int half = t >> 8;
  const int d = t & 255;
  const int kbase = half * D;
  float a0 = 0.f, a1 = 0.f, a2 = 0.f, a3 = 0.f;
  for (int kk = 0; kk < D; kk += 4) {
    const int k = kbase + kk;
    const float w0 = WfT[(k + 0) * D + d];
    const float w1 = WfT[(k + 1) * D + d];
    const float w2 = WfT[(k + 2) * D + d];
    const float w3 = WfT[(k + 3) * D + d];
    const float4 u0 = *(const float4*)&Us[0][k];
    const float4 u1 = *(const float4*)&Us[1][k];
    const float4 u2 = *(const float4*)&Us[2][k];
    const float4 u3 = *(const float4*)&Us[3][k];
    a0 = fmaf(w0, u0.x, a0); a0 = fmaf(w1, u0.y, a0); a0 = fmaf(w2, u0.z, a0); a0 = fmaf(w3, u0.w, a0);
    a1 = fmaf(w0, u1.x, a1); a1 = fmaf(w1, u1.y, a1); a1 = fmaf(w2, u1.z, a1); a1 = fmaf(w3, u1.w, a1);
    a2 = fmaf(w0, u2.x, a2); a2 = fmaf(w1, u2.y, a2); a2 = fmaf(w2, u2.z, a2); a2 = fmaf(w3, u2.w, a2);
    a3 = fmaf(w0, u3.x, a3); a3 = fmaf(w1, u3.y, a3); a3 = fmaf(w2, u3.z, a3); a3 = fmaf(w3, u3.w, a3);
  }
  if (half == 0) {
    part[0][d] = a0; part[1][d] = a1; part[2][d] = a2; part[3][d] = a3;
  }
  __syncthreads();
  if (half == 1) {
    part[0][d] += a0; part[1][d] += a1; part[2][d] += a2; part[3][d] += a3;
  }
  __syncthreads();
  if (t < D) {
    const float bb = b2[t];
    for (int r = 0; r < 4; ++r) {
      const int b = b0 + r;
      const int cnt = offs[b + 1] - offs[b];
      const float o = part[r][t] + bb;
      out[b * D + t] = (cnt > 0) ? o : Us[r][t];
    }
  }
}

extern "C" void kernel_launch(void* const* d_in, const int* in_sizes, int n_in,
                              void* d_out, int out_size, void* d_ws, size_t ws_size,
                              hipStream_t stream) {
  const float* V   = (const float*)d_in[0];
  const float* H   = (const float*)d_in[1];
  const int* bidx  = (const int*)d_in[2];
  const float* Wq  = (const float*)d_in[3];
  const float* bq  = (const float*)d_in[4];
  const float* Wk  = (const float*)d_in[5];
  const float* bk  = (const float*)d_in[6];
  const float* Wv  = (const float*)d_in[7];
  const float* bv  = (const float*)d_in[8];
  const float* Wo  = (const float*)d_in[9];
  const float* bo  = (const float*)d_in[10];
  float* out = (float*)d_out;

  float* ws = (float*)d_ws;
  float* MqT = ws;                    // 256*256
  float* WfT = MqT + D * D;           // 512*256
  float* bqt = WfT + TWOD * D;        // 256
  float* vq  = bqt + D;               // 256
  float* b2  = vq + D;                // 256
  float* c0  = b2 + D;                // 4 (1 used)
  float* qt  = c0 + 4;                // 1024*256
  float* cQ  = qt + BB * D;           // 1024
  float* sA  = cQ + BB;               // 1024*256
  int* offs  = (int*)(sA + BB * D);   // 1025

  hipLaunchKernelGGL(p0a_kernel, dim3(65), dim3(256), 0, stream,
                     Wq, bq, Wk, bk, MqT, bqt, vq, c0);
  hipLaunchKernelGGL(p0b_kernel, dim3(129), dim3(256), 0, stream,
                     Wo, Wv, bv, bo, WfT, b2);
  hipLaunchKernelGGL(koff_kernel, dim3(5), dim3(256), 0, stream, bidx, offs);
  hipLaunchKernelGGL(kq_kernel, dim3(BB / 4), dim3(256), 0, stream,
                     V, MqT, bqt, vq, c0, qt, cQ);
  hipLaunchKernelGGL(k1_kernel, dim3(BB), dim3(256), 0, stream,
                     H, qt, cQ, offs, sA);
  hipLaunchKernelGGL(k2_kernel, dim3(BB / 4), dim3(512), 0, stream,
                     V, sA, WfT, b2, offs, out);
}

// Round 2
// 65.027 us; speedup vs baseline: 1.6126x; 1.6126x over previous
//
#include <hip/hip_runtime.h>
#include <math.h>

#define D 256
#define TWOD 512
#define BB 1024
#define NN 131072
#define LOG2E 1.4426950408889634f

typedef float v4f __attribute__((ext_vector_type(4)));

// ---------------- pre: LDS-tiled transposes + segment offsets
// blocks 0..15  : WqT = Wq^T        (Wq [256][256])
// blocks 16..31 : WvT = Wv^T        (Wv [256][256])
// blocks 32..63 : WoT = Wo^T        (Wo [256][512] -> [512][256])
// blocks 64..68 : offs (lower_bound per batch id)
__global__ __launch_bounds__(256) void pre_kernel(
    const float* __restrict__ Wq, const float* __restrict__ Wv,
    const float* __restrict__ Wo, const int* __restrict__ bidx,
    float* __restrict__ WqT, float* __restrict__ WvT,
    float* __restrict__ WoT, int* __restrict__ offs) {
  const int blk = blockIdx.x;
  const int t = threadIdx.x;
  if (blk < 64) {
    __shared__ float tile[64][65];
    const float* src; float* dst; int r0, c0, C;
    if (blk < 16)      { src = Wq; dst = WqT; C = 256; r0 = (blk >> 2) * 64;        c0 = (blk & 3) * 64; }
    else if (blk < 32) { int b = blk - 16; src = Wv; dst = WvT; C = 256; r0 = (b >> 2) * 64; c0 = (b & 3) * 64; }
    else               { int b = blk - 32; src = Wo; dst = WoT; C = 512; r0 = (b >> 3) * 64; c0 = (b & 7) * 64; }
    const int lane = t & 63, sr = t >> 6;
    #pragma unroll 4
    for (int rr = 0; rr < 16; ++rr) {
      const int r = rr * 4 + sr;
      tile[r][lane] = src[(size_t)(r0 + r) * C + c0 + lane];
    }
    __syncthreads();
    #pragma unroll 4
    for (int rr = 0; rr < 16; ++rr) {
      const int r = rr * 4 + sr;
      dst[(size_t)(c0 + r) * 256 + r0 + lane] = tile[lane][r];
    }
  } else {
    const int i = (blk - 64) * 256 + t;
    if (i > BB) return;
    int lo = 0, hi = NN;
    while (lo < hi) {
      const int mid = (lo + hi) >> 1;
      if (bidx[mid] < i) lo = mid + 1; else hi = mid;
    }
    offs[i] = lo;
  }
}

// ---------------- kq: per-batch q1 = WqT^T V + bq ; qt = Wk(q1) ; cQ = bk.q1
// 256 blocks x 512 threads, 4 batches per block, D split in halves across t>>8
__global__ __launch_bounds__(512) void kq_kernel(
    const float* __restrict__ V, const float* __restrict__ WqT,
    const float* __restrict__ Wk, const float* __restrict__ bq,
    const float* __restrict__ bk,
    float* __restrict__ qt, float* __restrict__ cQ) {
  __shared__ __align__(16) float Vs[4][D];
  __shared__ __align__(16) float q1s[4][D];
  __shared__ __align__(16) float part[2][4][D];
  __shared__ float cqp[2][4];
  const int t = threadIdx.x;
  const int k = t & 255, hh = t >> 8;
  const int b0 = blockIdx.x * 4;

  for (int j = 0; j < 2; ++j) {
    const int i = hh * 2 + j;
    Vs[i][k] = V[(size_t)(b0 + i) * D + k];
  }
  __syncthreads();

  // stage 1: q1[i][k] partial over d in [hh*128, hh*128+128)
  {
    float a0 = 0.f, a1 = 0.f, a2 = 0.f, a3 = 0.f;
    const int dbase = hh * 128;
    #pragma unroll 2
    for (int d = dbase; d < dbase + 128; d += 4) {
      const float w0 = WqT[(size_t)(d + 0) * D + k];
      const float w1 = WqT[(size_t)(d + 1) * D + k];
      const float w2 = WqT[(size_t)(d + 2) * D + k];
      const float w3 = WqT[(size_t)(d + 3) * D + k];
      const float4 v0 = *(const float4*)&Vs[0][d];
      const float4 v1 = *(const float4*)&Vs[1][d];
      const float4 v2 = *(const float4*)&Vs[2][d];
      const float4 v3 = *(const float4*)&Vs[3][d];
      a0 = fmaf(w0, v0.x, a0); a0 = fmaf(w1, v0.y, a0); a0 = fmaf(w2, v0.z, a0); a0 = fmaf(w3, v0.w, a0);
      a1 = fmaf(w0, v1.x, a1); a1 = fmaf(w1, v1.y, a1); a1 = fmaf(w2, v1.z, a1); a1 = fmaf(w3, v1.w, a1);
      a2 = fmaf(w0, v2.x, a2); a2 = fmaf(w1, v2.y, a2); a2 = fmaf(w2, v2.z, a2); a2 = fmaf(w3, v2.w, a2);
      a3 = fmaf(w0, v3.x, a3); a3 = fmaf(w1, v3.y, a3); a3 = fmaf(w2, v3.z, a3); a3 = fmaf(w3, v3.w, a3);
    }
    part[hh][0][k] = a0; part[hh][1][k] = a1; part[hh][2][k] = a2; part[hh][3][k] = a3;
  }
  __syncthreads();
  for (int j = 0; j < 2; ++j) {
    const int i = hh * 2 + j;
    q1s[i][k] = part[0][i][k] + part[1][i][k] + bq[k];
  }
  __syncthreads();

  // stage 2: qt[i][h] partial over kk in [hh*128, +128)  (h = k thread index)
  {
    float a0 = 0.f, a1 = 0.f, a2 = 0.f, a3 = 0.f;
    const int kbase = hh * 128;
    #pragma unroll 2
    for (int kk = kbase; kk < kbase + 128; kk += 4) {
      const float w0 = Wk[(size_t)(kk + 0) * D + k];
      const float w1 = Wk[(size_t)(kk + 1) * D + k];
      const float w2 = Wk[(size_t)(kk + 2) * D + k];
      const float w3 = Wk[(size_t)(kk + 3) * D + k];
      const float4 q0 = *(const float4*)&q1s[0][kk];
      const float4 q1 = *(const float4*)&q1s[1][kk];
      const float4 q2 = *(const float4*)&q1s[2][kk];
      const float4 q3 = *(const float4*)&q1s[3][kk];
      a0 = fmaf(w0, q0.x, a0); a0 = fmaf(w1, q0.y, a0); a0 = fmaf(w2, q0.z, a0); a0 = fmaf(w3, q0.w, a0);
      a1 = fmaf(w0, q1.x, a1); a1 = fmaf(w1, q1.y, a1); a1 = fmaf(w2, q1.z, a1); a1 = fmaf(w3, q1.w, a1);
      a2 = fmaf(w0, q2.x, a2); a2 = fmaf(w1, q2.y, a2); a2 = fmaf(w2, q2.z, a2); a2 = fmaf(w3, q2.w, a2);
      a3 = fmaf(w0, q3.x, a3); a3 = fmaf(w1, q3.y, a3); a3 = fmaf(w2, q3.z, a3); a3 = fmaf(w3, q3.w, a3);
    }
    part[hh][0][k] = a0; part[hh][1][k] = a1; part[hh][2][k] = a2; part[hh][3][k] = a3;
  }
  // cQ partials: wave w -> batch (w>>1), half (w&1)
  {
    const int wave = t >> 6, lane = t & 63;
    const int i = wave >> 1, hf = wave & 1;
    const int kk = hf * 128 + lane * 2;
    float p = bk[kk] * q1s[i][kk] + bk[kk + 1] * q1s[i][kk + 1];
    p += __shfl_xor(p, 32);
    p += __shfl_xor(p, 16);
    p += __shfl_xor(p, 8);
    p += __shfl_xor(p, 4);
    p += __shfl_xor(p, 2);
    p += __shfl_xor(p, 1);
    if (lane == 0) cqp[hf][i] = p;
  }
  __syncthreads();
  for (int j = 0; j < 2; ++j) {
    const int i = hh * 2 + j;
    qt[(size_t)(b0 + i) * D + k] = part[0][i][k] + part[1][i][k];
  }
  if (t < 4) cQ[b0 + t] = cqp[0][t] + cqp[1][t];
}

// ---------------- k1: flash pass, 2 blocks per batch (contiguous halves)
__global__ __launch_bounds__(256) void k1_kernel(
    const float* __restrict__ H, const float* __restrict__ qt,
    const float* __restrict__ cQ, const int* __restrict__ offs,
    float* __restrict__ sP, float* __restrict__ mP, float* __restrict__ dP) {
  const int blk = blockIdx.x;
  const int b = blk >> 1, half = blk & 1;
  const int t = threadIdx.x, wave = t >> 6, lane = t & 63;
  const int start = offs[b], end = offs[b + 1];
  const int cnt = end - start;
  const int mid = start + ((cnt + 1) >> 1);
  const int s0 = half ? mid : start;
  const int e0 = half ? end : mid;
  if (s0 >= e0) {
    sP[(size_t)blk * D + t] = 0.f;
    if (t == 0) { mP[blk] = -1e30f; dP[blk] = 0.f; }
    return;
  }
  const float4 q4 = *(const float4*)&qt[(size_t)b * D + lane * 4];
  const float SC = 0.0625f * LOG2E;
  const float cbs = cQ[b] * SC;

  float m = -1e30f, den = 0.f;
  float ax = 0.f, ay = 0.f, az = 0.f, aw = 0.f;

  int n = s0 + wave;
  v4f cur = {0.f, 0.f, 0.f, 0.f};
  if (n < e0) cur = __builtin_nontemporal_load((const v4f*)(H + (size_t)n * D + lane * 4));
  while (n < e0) {
    const int nn = n + 4;
    v4f nxt = cur;
    if (nn < e0) nxt = __builtin_nontemporal_load((const v4f*)(H + (size_t)nn * D + lane * 4));

    float p = cur.x * q4.x;
    p = fmaf(cur.y, q4.y, p);
    p = fmaf(cur.z, q4.z, p);
    p = fmaf(cur.w, q4.w, p);
    p += __shfl_xor(p, 32);
    p += __shfl_xor(p, 16);
    p += __shfl_xor(p, 8);
    p += __shfl_xor(p, 4);
    p += __shfl_xor(p, 2);
    p += __shfl_xor(p, 1);
    const float s2 = fmaf(p, SC, cbs);      // log2-domain score

    const float nm = fmaxf(m, s2);
    const float f = exp2f(m - nm);
    const float w = exp2f(s2 - nm);
    den = fmaf(den, f, w);
    ax = fmaf(w, cur.x, ax * f);
    ay = fmaf(w, cur.y, ay * f);
    az = fmaf(w, cur.z, az * f);
    aw = fmaf(w, cur.w, aw * f);
    m = nm;

    cur = nxt;
    n = nn;
  }

  __shared__ float sm[4], sd[4];
  __shared__ __align__(16) float ss[4][D];
  ss[wave][lane * 4 + 0] = ax;
  ss[wave][lane * 4 + 1] = ay;
  ss[wave][lane * 4 + 2] = az;
  ss[wave][lane * 4 + 3] = aw;
  if (lane == 0) { sm[wave] = m; sd[wave] = den; }
  __syncthreads();

  const float M = fmaxf(fmaxf(sm[0], sm[1]), fmaxf(sm[2], sm[3]));
  float Dn = 0.f, val = 0.f;
  #pragma unroll
  for (int w2 = 0; w2 < 4; ++w2) {
    const float f = exp2f(sm[w2] - M);
    Dn = fmaf(sd[w2], f, Dn);
    val = fmaf(ss[w2][t], f, val);
  }
  sP[(size_t)blk * D + t] = val;
  if (t == 0) { mP[blk] = M; dP[blk] = Dn; }
}

// ---------------- k2: merge partials -> sN ; H~ = WvT^T sN + bv ; out = WoT^T [V;H~] + bo
// 256 blocks x 512 threads, 4 batches per block, sums split across t>>8
__global__ __launch_bounds__(512) void k2_kernel(
    const float* __restrict__ V, const float* __restrict__ WvT,
    const float* __restrict__ WoT, const float* __restrict__ bv,
    const float* __restrict__ bo, const float* __restrict__ sP,
    const float* __restrict__ mP, const float* __restrict__ dP,
    const int* __restrict__ offs, float* __restrict__ out) {
  __shared__ __align__(16) float sN[4][D];
  __shared__ __align__(16) float Us[4][TWOD];
  __shared__ __align__(16) float part[2][4][D];
  const int t = threadIdx.x;
  const int d = t & 255, hh = t >> 8;
  const int b0 = blockIdx.x * 4;

  for (int j = 0; j < 2; ++j) {
    const int i = hh * 2 + j;
    const int b = b0 + i;
    const float m0 = mP[2 * b], m1 = mP[2 * b + 1];
    const float d0 = dP[2 * b], d1 = dP[2 * b + 1];
    const float M = fmaxf(m0, m1);
    const float f0 = exp2f(m0 - M), f1 = exp2f(m1 - M);
    const float Dn = d0 * f0 + d1 * f1;
    const float inv = (Dn > 0.f) ? (1.f / Dn) : 0.f;
    sN[i][d] = (sP[(size_t)(2 * b) * D + d] * f0 + sP[(size_t)(2 * b + 1) * D + d] * f1) * inv;
    Us[i][d] = V[(size_t)b * D + d];
  }
  __syncthreads();

  // r-stage: H~ partials over h in [hh*128, +128)
  {
    float a0 = 0.f, a1 = 0.f, a2 = 0.f, a3 = 0.f;
    const int hbase = hh * 128;
    #pragma unroll 2
    for (int h = hbase; h < hbase + 128; h += 4) {
      const float w0 = WvT[(size_t)(h + 0) * D + d];
      const float w1 = WvT[(size_t)(h + 1) * D + d];
      const float w2 = WvT[(size_t)(h + 2) * D + d];
      const float w3 = WvT[(size_t)(h + 3) * D + d];
      const float4 s0 = *(const float4*)&sN[0][h];
      const float4 s1 = *(const float4*)&sN[1][h];
      const float4 s2 = *(const float4*)&sN[2][h];
      const float4 s3 = *(const float4*)&sN[3][h];
      a0 = fmaf(w0, s0.x, a0); a0 = fmaf(w1, s0.y, a0); a0 = fmaf(w2, s0.z, a0); a0 = fmaf(w3, s0.w, a0);
      a1 = fmaf(w0, s1.x, a1); a1 = fmaf(w1, s1.y, a1); a1 = fmaf(w2, s1.z, a1); a1 = fmaf(w3, s1.w, a1);
      a2 = fmaf(w0, s2.x, a2); a2 = fmaf(w1, s2.y, a2); a2 = fmaf(w2, s2.z, a2); a2 = fmaf(w3, s2.w, a2);
      a3 = fmaf(w0, s3.x, a3); a3 = fmaf(w1, s3.y, a3); a3 = fmaf(w2, s3.z, a3); a3 = fmaf(w3, s3.w, a3);
    }
    part[hh][0][d] = a0; part[hh][1][d] = a1; part[hh][2][d] = a2; part[hh][3][d] = a3;
  }
  __syncthreads();
  for (int j = 0; j < 2; ++j) {
    const int i = hh * 2 + j;
    Us[i][D + d] = part[0][i][d] + part[1][i][d] + bv[d];
  }
  __syncthreads();

  // out-stage: out partials over kk in [hh*256, +256)
  {
    float a0 = 0.f, a1 = 0.f, a2 = 0.f, a3 = 0.f;
    const int kbase = hh * 256;
    #pragma unroll 2
    for (int kk = kbase; kk < kbase + 256; kk += 4) {
      const float w0 = WoT[(size_t)(kk + 0) * D + d];
      const float w1 = WoT[(size_t)(kk + 1) * D + d];
      const float w2 = WoT[(size_t)(kk + 2) * D + d];
      const float w3 = WoT[(size_t)(kk + 3) * D + d];
      const float4 u0 = *(const float4*)&Us[0][kk];
      const float4 u1 = *(const float4*)&Us[1][kk];
      const float4 u2 = *(const float4*)&Us[2][kk];
      const float4 u3 = *(const float4*)&Us[3][kk];
      a0 = fmaf(w0, u0.x, a0); a0 = fmaf(w1, u0.y, a0); a0 = fmaf(w2, u0.z, a0); a0 = fmaf(w3, u0.w, a0);
      a1 = fmaf(w0, u1.x, a1); a1 = fmaf(w1, u1.y, a1); a1 = fmaf(w2, u1.z, a1); a1 = fmaf(w3, u1.w, a1);
      a2 = fmaf(w0, u2.x, a2); a2 = fmaf(w1, u2.y, a2); a2 = fmaf(w2, u2.z, a2); a2 = fmaf(w3, u2.w, a2);
      a3 = fmaf(w0, u3.x, a3); a3 = fmaf(w1, u3.y, a3); a3 = fmaf(w2, u3.z, a3); a3 = fmaf(w3, u3.w, a3);
    }
    part[hh][0][d] = a0; part[hh][1][d] = a1; part[hh][2][d] = a2; part[hh][3][d] = a3;
  }
  __syncthreads();
  for (int j = 0; j < 2; ++j) {
    const int i = hh * 2 + j;
    const int b = b0 + i;
    const int cnt = offs[b + 1] - offs[b];
    const float o = part[0][i][d] + part[1][i][d] + bo[d];
    out[(size_t)b * D + d] = (cnt > 0) ? o : Us[i][d];
  }
}

extern "C" void kernel_launch(void* const* d_in, const int* in_sizes, int n_in,
                              void* d_out, int out_size, void* d_ws, size_t ws_size,
                              hipStream_t stream) {
  const float* V   = (const float*)d_in[0];
  const float* H   = (const float*)d_in[1];
  const int* bidx  = (const int*)d_in[2];
  const float* Wq  = (const float*)d_in[3];
  const float* bq  = (const float*)d_in[4];
  const float* Wk  = (const float*)d_in[5];
  const float* bk  = (const float*)d_in[6];
  const float* Wv  = (const float*)d_in[7];
  const float* bv  = (const float*)d_in[8];
  const float* Wo  = (const float*)d_in[9];
  const float* bo  = (const float*)d_in[10];
  float* out = (float*)d_out;

  float* ws  = (float*)d_ws;
  float* WqT = ws;                       // 256*256
  float* WvT = WqT + D * D;              // 256*256
  float* WoT = WvT + D * D;              // 512*256
  float* qt  = WoT + TWOD * D;           // 1024*256
  float* cQ  = qt + BB * D;              // 1024
  float* sP  = cQ + BB;                  // 2048*256
  float* mP  = sP + 2 * BB * D;          // 2048
  float* dP  = mP + 2 * BB;              // 2048
  int* offs  = (int*)(dP + 2 * BB);      // 1025

  hipLaunchKernelGGL(pre_kernel, dim3(69), dim3(256), 0, stream,
                     Wq, Wv, Wo, bidx, WqT, WvT, WoT, offs);
  hipLaunchKernelGGL(kq_kernel, dim3(BB / 4), dim3(512), 0, stream,
                     V, WqT, Wk, bq, bk, qt, cQ);
  hipLaunchKernelGGL(k1_kernel, dim3(2 * BB), dim3(256), 0, stream,
                     H, qt, cQ, offs, sP, mP, dP);
  hipLaunchKernelGGL(k2_kernel, dim3(BB / 4), dim3(512), 0, stream,
                     V, WvT, WoT, bv, bo, sP, mP, dP, offs, out);
}

// Round 3
// 60.491 us; speedup vs baseline: 1.7335x; 1.0750x over previous
//
#include <hip/hip_runtime.h>
#include <math.h>

#define D 256
#define TWOD 512
#define BB 1024
#define NN 131072
#define LOG2E 1.4426950408889634f

typedef float v4f __attribute__((ext_vector_type(4)));

// ---------------- pre: LDS-tiled transposes + segment offsets
// blocks 0..15  : WqT = Wq^T   (Wq [256][256])
// blocks 16..31 : WvT = Wv^T   (Wv [256][256])
// blocks 32..63 : WoT = Wo^T   (Wo [256][512] -> [512][256])
// blocks 64..68 : offs (lower_bound per batch id)
__global__ __launch_bounds__(256) void pre_kernel(
    const float* __restrict__ Wq, const float* __restrict__ Wv,
    const float* __restrict__ Wo, const int* __restrict__ bidx,
    float* __restrict__ WqT, float* __restrict__ WvT,
    float* __restrict__ WoT, int* __restrict__ offs) {
  const int blk = blockIdx.x;
  const int t = threadIdx.x;
  if (blk < 64) {
    __shared__ float tile[64][65];
    const float* src; float* dst; int r0, c0, C;
    if (blk < 16)      { src = Wq; dst = WqT; C = 256; r0 = (blk >> 2) * 64;        c0 = (blk & 3) * 64; }
    else if (blk < 32) { int b = blk - 16; src = Wv; dst = WvT; C = 256; r0 = (b >> 2) * 64; c0 = (b & 3) * 64; }
    else               { int b = blk - 32; src = Wo; dst = WoT; C = 512; r0 = (b >> 3) * 64; c0 = (b & 7) * 64; }
    const int lane = t & 63, sr = t >> 6;
    #pragma unroll 4
    for (int rr = 0; rr < 16; ++rr) {
      const int r = rr * 4 + sr;
      tile[r][lane] = src[(size_t)(r0 + r) * C + c0 + lane];
    }
    __syncthreads();
    #pragma unroll 4
    for (int rr = 0; rr < 16; ++rr) {
      const int r = rr * 4 + sr;
      dst[(size_t)(c0 + r) * 256 + r0 + lane] = tile[lane][r];
    }
  } else {
    const int i = (blk - 64) * 256 + t;
    if (i > BB) return;
    int lo = 0, hi = NN;
    while (lo < hi) {
      const int mid = (lo + hi) >> 1;
      if (bidx[mid] < i) lo = mid + 1; else hi = mid;
    }
    offs[i] = lo;
  }
}

// ---------------- kq: q1 = Wq V + bq ; qt = Wk^T q1   (scalar-broadcast GEMM)
// 256 blocks x 512 threads (8 waves); 4 batches per block.
__global__ __launch_bounds__(512) void kq_kernel(
    const float* __restrict__ V, const float* __restrict__ WqT,
    const float* __restrict__ Wk, const float* __restrict__ bq,
    float* __restrict__ qt) {
  __shared__ __align__(16) float part[8][4][D];   // wave partials
  __shared__ __align__(16) float q1s4[D][4];      // q1 packed [k][batch]
  const int t = threadIdx.x;
  const int wq = __builtin_amdgcn_readfirstlane(t >> 6);
  const int lane = t & 63;
  const int k4 = lane * 4;
  const int b0 = blockIdx.x * 4;

  // ---- phase A: q1[i][k] partials, wave wq covers d in [wq*32, +32)
  {
    v4f a0 = {0,0,0,0}, a1 = a0, a2 = a0, a3 = a0;
    const int dbase = wq * 32;
    for (int dd = 0; dd < 32; dd += 4) {
      const int d = dbase + dd;
      const v4f vv0 = *(const v4f*)(V + (size_t)(b0 + 0) * D + d);  // wave-uniform -> s_load
      const v4f vv1 = *(const v4f*)(V + (size_t)(b0 + 1) * D + d);
      const v4f vv2 = *(const v4f*)(V + (size_t)(b0 + 2) * D + d);
      const v4f vv3 = *(const v4f*)(V + (size_t)(b0 + 3) * D + d);
      #pragma unroll
      for (int j = 0; j < 4; ++j) {
        const v4f w4 = *(const v4f*)(WqT + (size_t)(d + j) * D + k4);
        a0 += w4 * vv0[j]; a1 += w4 * vv1[j]; a2 += w4 * vv2[j]; a3 += w4 * vv3[j];
      }
    }
    *(v4f*)&part[wq][0][k4] = a0;
    *(v4f*)&part[wq][1][k4] = a1;
    *(v4f*)&part[wq][2][k4] = a2;
    *(v4f*)&part[wq][3][k4] = a3;
  }
  __syncthreads();
  // reduce 8 wave-partials -> q1s4[k][i]
  {
    const int k = t & 255;
    const int ib = (t >> 8) * 2;
    #pragma unroll
    for (int j = 0; j < 2; ++j) {
      const int i = ib + j;
      float s = bq[k];
      #pragma unroll
      for (int w = 0; w < 8; ++w) s += part[w][i][k];
      q1s4[k][i] = s;
    }
  }
  __syncthreads();

  // ---- phase B: qt[i][h] partials, wave wq covers k in [wq*32, +32)
  {
    v4f a0 = {0,0,0,0}, a1 = a0, a2 = a0, a3 = a0;
    const int kbase = wq * 32;
    for (int kk = 0; kk < 32; ++kk) {
      const int k = kbase + kk;
      const v4f w4 = *(const v4f*)(Wk + (size_t)k * D + k4);   // Wk[k][h] coalesced
      const v4f q  = *(const v4f*)&q1s4[k][0];                 // LDS broadcast b128
      a0 += w4 * q.x; a1 += w4 * q.y; a2 += w4 * q.z; a3 += w4 * q.w;
    }
    *(v4f*)&part[wq][0][k4] = a0;
    *(v4f*)&part[wq][1][k4] = a1;
    *(v4f*)&part[wq][2][k4] = a2;
    *(v4f*)&part[wq][3][k4] = a3;
  }
  __syncthreads();
  {
    const int h = t & 255;
    const int ib = (t >> 8) * 2;
    #pragma unroll
    for (int j = 0; j < 2; ++j) {
      const int i = ib + j;
      float s = 0.f;
      #pragma unroll
      for (int w = 0; w < 8; ++w) s += part[w][i][h];
      qt[(size_t)(b0 + i) * D + h] = s;
    }
  }
}

// ---------------- k1: flash pass, 2 blocks per batch, 2 rows/wave/iter
__global__ __launch_bounds__(256) void k1_kernel(
    const float* __restrict__ H, const float* __restrict__ qt,
    const int* __restrict__ offs,
    float* __restrict__ sP, float* __restrict__ mP, float* __restrict__ dP) {
  const int blk = blockIdx.x;
  const int b = blk >> 1, half = blk & 1;
  const int t = threadIdx.x, wave = t >> 6, lane = t & 63;
  const int start = offs[b], end = offs[b + 1];
  const int cnt = end - start;
  const int mid = start + ((cnt + 1) >> 1);
  const int s0 = half ? mid : start;
  const int e0 = half ? end : mid;
  if (s0 >= e0) {
    sP[(size_t)blk * D + t] = 0.f;
    if (t == 0) { mP[blk] = -1e30f; dP[blk] = 0.f; }
    return;
  }
  const v4f q4 = *(const v4f*)(qt + (size_t)b * D + lane * 4);
  const float SC = 0.0625f * LOG2E;

  float m = -1e30f, den = 0.f;
  v4f acc = {0,0,0,0};

  int n = s0 + wave * 2;
  v4f c0 = {0,0,0,0}, c1 = {0,0,0,0};
  if (n < e0)     c0 = __builtin_nontemporal_load((const v4f*)(H + (size_t)n * D + lane * 4));
  if (n + 1 < e0) c1 = __builtin_nontemporal_load((const v4f*)(H + (size_t)(n + 1) * D + lane * 4));
  while (n < e0) {
    const int nn = n + 8;
    v4f p0 = {0,0,0,0}, p1 = {0,0,0,0};
    if (nn < e0)     p0 = __builtin_nontemporal_load((const v4f*)(H + (size_t)nn * D + lane * 4));
    if (nn + 1 < e0) p1 = __builtin_nontemporal_load((const v4f*)(H + (size_t)(nn + 1) * D + lane * 4));

    float d0 = c0.x * q4.x;            float d1 = c1.x * q4.x;
    d0 = fmaf(c0.y, q4.y, d0);         d1 = fmaf(c1.y, q4.y, d1);
    d0 = fmaf(c0.z, q4.z, d0);         d1 = fmaf(c1.z, q4.z, d1);
    d0 = fmaf(c0.w, q4.w, d0);         d1 = fmaf(c1.w, q4.w, d1);
    d0 += __shfl_xor(d0, 32);          d1 += __shfl_xor(d1, 32);
    d0 += __shfl_xor(d0, 16);          d1 += __shfl_xor(d1, 16);
    d0 += __shfl_xor(d0, 8);           d1 += __shfl_xor(d1, 8);
    d0 += __shfl_xor(d0, 4);           d1 += __shfl_xor(d1, 4);
    d0 += __shfl_xor(d0, 2);           d1 += __shfl_xor(d1, 2);
    d0 += __shfl_xor(d0, 1);           d1 += __shfl_xor(d1, 1);

    const float sa = d0 * SC;
    const float sb = (n + 1 < e0) ? d1 * SC : -1e30f;
    const float nm = fmaxf(fmaxf(m, sa), sb);      // v_max3
    const float f  = exp2f(m - nm);
    const float wa = exp2f(sa - nm);
    const float wb = exp2f(sb - nm);
    den = den * f + wa + wb;
    acc = acc * f + c0 * wa + c1 * wb;
    m = nm;

    c0 = p0; c1 = p1; n = nn;
  }

  __shared__ float sm[4], sd[4];
  __shared__ __align__(16) float ss[4][D];
  *(v4f*)&ss[wave][lane * 4] = acc;
  if (lane == 0) { sm[wave] = m; sd[wave] = den; }
  __syncthreads();

  const float M = fmaxf(fmaxf(sm[0], sm[1]), fmaxf(sm[2], sm[3]));
  float Dn = 0.f, val = 0.f;
  #pragma unroll
  for (int w2 = 0; w2 < 4; ++w2) {
    const float f = exp2f(sm[w2] - M);
    Dn = fmaf(sd[w2], f, Dn);
    val = fmaf(ss[w2][t], f, val);
  }
  sP[(size_t)blk * D + t] = val;
  if (t == 0) { mP[blk] = M; dP[blk] = Dn; }
}

// ---------------- k2: merge partials -> sN ; H~ = Wv sN + bv ; out = Wo [V;H~] + bo
// 256 blocks x 512 threads (8 waves); scalar-broadcast GEMMs.
__global__ __launch_bounds__(512) void k2_kernel(
    const float* __restrict__ V, const float* __restrict__ WvT,
    const float* __restrict__ WoT, const float* __restrict__ bv,
    const float* __restrict__ bo, const float* __restrict__ sP,
    const float* __restrict__ mP, const float* __restrict__ dP,
    const int* __restrict__ offs, float* __restrict__ out) {
  __shared__ __align__(16) float part[8][4][D];   // wave partials
  __shared__ __align__(16) float sN4[D][4];       // attn-avg H rows, [h][batch]
  __shared__ __align__(16) float Us4[TWOD][4];    // U = [V; H~], [k][batch]
  const int t = threadIdx.x;
  const int wq = __builtin_amdgcn_readfirstlane(t >> 6);
  const int lane = t & 63;
  const int dv4 = lane * 4;
  const int b0 = blockIdx.x * 4;

  // ---- phase 0: merge the two k1 halves per batch; stage V
  {
    const int d = t & 255;
    const int ib = (t >> 8) * 2;
    #pragma unroll
    for (int j = 0; j < 2; ++j) {
      const int i = ib + j;
      const int bb = b0 + i;
      const float m0 = mP[2 * bb], m1 = mP[2 * bb + 1];
      const float d0 = dP[2 * bb], d1 = dP[2 * bb + 1];
      const float M = fmaxf(m0, m1);
      const float f0 = exp2f(m0 - M), f1 = exp2f(m1 - M);
      const float Dn = d0 * f0 + d1 * f1;
      const float inv = (Dn > 0.f) ? (1.f / Dn) : 0.f;
      sN4[d][i] = (sP[(size_t)(2 * bb) * D + d] * f0 +
                   sP[(size_t)(2 * bb + 1) * D + d] * f1) * inv;
      Us4[d][i] = V[(size_t)bb * D + d];
    }
  }
  __syncthreads();

  // ---- phase A: H~[i][dv] partials, wave wq covers h in [wq*32, +32)
  {
    v4f a0 = {0,0,0,0}, a1 = a0, a2 = a0, a3 = a0;
    const int hbase = wq * 32;
    for (int hh = 0; hh < 32; ++hh) {
      const int h = hbase + hh;
      const v4f w4 = *(const v4f*)(WvT + (size_t)h * D + dv4);
      const v4f s4 = *(const v4f*)&sN4[h][0];                  // broadcast b128
      a0 += w4 * s4.x; a1 += w4 * s4.y; a2 += w4 * s4.z; a3 += w4 * s4.w;
    }
    *(v4f*)&part[wq][0][dv4] = a0;
    *(v4f*)&part[wq][1][dv4] = a1;
    *(v4f*)&part[wq][2][dv4] = a2;
    *(v4f*)&part[wq][3][dv4] = a3;
  }
  __syncthreads();
  {
    const int d = t & 255;
    const int ib = (t >> 8) * 2;
    #pragma unroll
    for (int j = 0; j < 2; ++j) {
      const int i = ib + j;
      float s = bv[d];
      #pragma unroll
      for (int w = 0; w < 8; ++w) s += part[w][i][d];
      Us4[D + d][i] = s;
    }
  }
  __syncthreads();

  // ---- phase B: out[i][dv] partials, wave wq covers k in [wq*64, +64)
  {
    v4f a0 = {0,0,0,0}, a1 = a0, a2 = a0, a3 = a0;
    const int kbase = wq * 64;
    for (int kk = 0; kk < 64; ++kk) {
      const int k = kbase + kk;
      const v4f w4 = *(const v4f*)(WoT + (size_t)k * D + dv4);
      const v4f u4 = *(const v4f*)&Us4[k][0];                  // broadcast b128
      a0 += w4 * u4.x; a1 += w4 * u4.y; a2 += w4 * u4.z; a3 += w4 * u4.w;
    }
    *(v4f*)&part[wq][0][dv4] = a0;
    *(v4f*)&part[wq][1][dv4] = a1;
    *(v4f*)&part[wq][2][dv4] = a2;
    *(v4f*)&part[wq][3][dv4] = a3;
  }
  __syncthreads();
  {
    const int d = t & 255;
    const int ib = (t >> 8) * 2;
    #pragma unroll
    for (int j = 0; j < 2; ++j) {
      const int i = ib + j;
      const int bb = b0 + i;
      float s = bo[d];
      #pragma unroll
      for (int w = 0; w < 8; ++w) s += part[w][i][d];
      const int c = offs[bb + 1] - offs[bb];
      out[(size_t)bb * D + d] = (c > 0) ? s : Us4[d][i];
    }
  }
}

extern "C" void kernel_launch(void* const* d_in, const int* in_sizes, int n_in,
                              void* d_out, int out_size, void* d_ws, size_t ws_size,
                              hipStream_t stream) {
  const float* V   = (const float*)d_in[0];
  const float* H   = (const float*)d_in[1];
  const int* bidx  = (const int*)d_in[2];
  const float* Wq  = (const float*)d_in[3];
  const float* bq  = (const float*)d_in[4];
  const float* Wk  = (const float*)d_in[5];
  const float* bv  = (const float*)d_in[8];
  const float* Wv  = (const float*)d_in[7];
  const float* Wo  = (const float*)d_in[9];
  const float* bo  = (const float*)d_in[10];
  float* out = (float*)d_out;

  float* ws  = (float*)d_ws;
  float* WqT = ws;                       // 256*256
  float* WvT = WqT + D * D;              // 256*256
  float* WoT = WvT + D * D;              // 512*256
  float* qt  = WoT + TWOD * D;           // 1024*256
  float* sP  = qt + BB * D;              // 2048*256
  float* mP  = sP + 2 * BB * D;          // 2048
  float* dP  = mP + 2 * BB;              // 2048
  int* offs  = (int*)(dP + 2 * BB);      // 1025

  hipLaunchKernelGGL(pre_kernel, dim3(69), dim3(256), 0, stream,
                     Wq, Wv, Wo, bidx, WqT, WvT, WoT, offs);
  hipLaunchKernelGGL(kq_kernel, dim3(BB / 4), dim3(512), 0, stream,
                     V, WqT, Wk, bq, qt);
  hipLaunchKernelGGL(k1_kernel, dim3(2 * BB), dim3(256), 0, stream,
                     H, qt, offs, sP, mP, dP);
  hipLaunchKernelGGL(k2_kernel, dim3(BB / 4), dim3(512), 0, stream,
                     V, WvT, WoT, bv, bo, sP, mP, dP, offs, out);
}